// Round 9
// baseline (236.555 us; speedup 1.0000x reference)
//
#include <hip/hip_runtime.h>

#define BB 256
#define LL 2048
#define HH 64
#define TT 64             // chunk length along L
#define SS 68             // padded LDS row stride (floats); 68%8==4 keeps b128 reads 2-way
#define NSEG 2            // L split across blocks
#define SEGL (LL / NSEG)  // 1024
#define NCSEG (SEGL / TT) // 16 real chunks per segment
#define NWARM 2           // warm-up chunks (128 steps) for z>0; carry error ~<=1e-4
#define NTOT (BB * LL * 2)

typedef __attribute__((ext_vector_type(8))) short bf16x8;
typedef __attribute__((ext_vector_type(4))) float f32x4;

__device__ __forceinline__ float rcp_(float x) { return __builtin_amdgcn_rcpf(x); }

// RNE fp32->bf16
__device__ __forceinline__ short f2bf_rne(float f) {
    union { float f; unsigned u; } v; v.f = f;
    unsigned r = v.u + 0x7fff + ((v.u >> 16) & 1);
    return (short)(r >> 16);
}

// DPP quad_perm: 0x90 = shift-up-1, 0x44 = shift-up-2, 0xFF = bcast lane3 of quad.
template<int CTRL>
__device__ __forceinline__ float qdpp(float x) {
    union { float f; int i; } u, r;
    u.f = x;
    r.i = __builtin_amdgcn_update_dpp(0, u.i, CTRL, 0xF, 0xF, false);
    return r.f;
}

// DPP row_shr:D, zero bound: lane i gets lane i-D within its 16-lane row.
template<int D>
__device__ __forceinline__ float rshr(float x) {
    union { float f; int i; } u, r;
    u.f = x;
    r.i = __builtin_amdgcn_update_dpp(0, u.i, 0x110 | D, 0xF, 0xF, true);
    return r.f;
}

// Layer-0 gates from 16-bit mask + LUT, 64-step scan (16 local + quad DPP scan),
// writes h0 to sh with the bit4 column swizzle. Gates recomputed from bits in the
// apply pass (no ai/bi arrays -> low register pressure).
__device__ __forceinline__ void p1_scan(unsigned bits,
                                        float a0v, float b0v, float a1v, float b1v,
                                        int seg, int col0, float& carry, float* sh)
{
    float A = 1.0f, Bv = 0.0f;
    #pragma unroll
    for (int i = 0; i < 16; ++i) {
        const bool on = (bits >> i) & 1u;
        const float ai = on ? a1v : a0v;
        const float bi = on ? b1v : b0v;
        A  = A * ai;
        Bv = fmaf(Bv, ai, bi);
    }
    {
        const float Au = qdpp<0x90>(A), Bu = qdpp<0x90>(Bv);
        if (seg >= 1) { const float Ac = A; A = Au * Ac; Bv = fmaf(Bu, Ac, Bv); }
        const float Au2 = qdpp<0x44>(A), Bu2 = qdpp<0x44>(Bv);
        if (seg >= 2) { const float Ac = A; A = Au2 * Ac; Bv = fmaf(Bu2, Ac, Bv); }
    }
    float Ae = qdpp<0x90>(A), Be = qdpp<0x90>(Bv);
    if (seg == 0) { Ae = 1.0f; Be = 0.0f; }
    float cc = fmaf(Ae, carry, Be);
    #pragma unroll
    for (int i = 0; i < 16; ++i) {
        const bool on = (bits >> i) & 1u;
        const float ai = on ? a1v : a0v;
        const float bi = on ? b1v : b0v;
        cc = fmaf(ai, cc, bi);
        sh[(seg * 16 + i) * SS + col0] = cc;
    }
    carry = qdpp<0xFF>(cc);   // broadcast quad lane-3 final state
}

__global__ void __launch_bounds__(256)
__attribute__((amdgpu_waves_per_eu(4, 4)))   // 4 waves/EU -> 4 blocks/CU, 128 VGPR cap
gru_fused(const float* __restrict__ x, const int* __restrict__ p,
               const float* __restrict__ w1z0, const float* __restrict__ b1z0,
               const float* __restrict__ w1h0, const float* __restrict__ b1h0,
               const float* __restrict__ w1z1, const float* __restrict__ b1z1,
               const float* __restrict__ w1h1, const float* __restrict__ b1h1,
               const float* __restrict__ w1o,  const float* __restrict__ b1o,
               const float* __restrict__ w2z0, const float* __restrict__ b2z0,
               const float* __restrict__ w2h0, const float* __restrict__ b2h0,
               const float* __restrict__ w2z1, const float* __restrict__ b2z1,
               const float* __restrict__ w2h1, const float* __restrict__ b2h1,
               const float* __restrict__ w2o,  const float* __restrict__ b2o,
               float* __restrict__ out, float* __restrict__ ws)
{
    const int  b  = blockIdx.x;
    const bool pm = (blockIdx.y != 0);
    const int  z  = blockIdx.z;                 // L-segment index
    const int nwarm  = z ? NWARM : 0;
    const int NC     = NCSEG + nwarm;           // local chunks incl. warm-up
    const int tstart = z * SEGL - nwarm * TT;   // 0 or 896

    const float* wz0 = pm ? w2z0 : w1z0;
    const float* bz0 = pm ? b2z0 : b1z0;
    const float* wh0 = pm ? w2h0 : w1h0;
    const float* bh0 = pm ? b2h0 : b1h0;
    const float* wz1 = pm ? w2z1 : w1z1;
    const float* bz1 = pm ? b2z1 : b1z1;
    const float* wh1 = pm ? w2h1 : w1h1;
    const float* bh1 = pm ? b2h1 : b1h1;
    const float* wo  = pm ? w2o  : w1o;
    const float* bov = pm ? b2o  : b1o;

    const int tid  = threadIdx.x;
    const int lane = tid & 63;
    const int tg   = tid >> 6;          // wave id; owns t-block [16*tg, 16*tg+16)
    const int q    = lane >> 4;         // MFMA quad
    const int n    = lane & 15;         // MFMA col (h low bits)
    const int seg  = lane & 3;          // P1 segment
    const int hidx = (tg << 4) | (lane >> 2);

    __shared__ __align__(16) float s_h[2 * TT * SS];   // double-buffered h0 (swizzled)
    __shared__ float2 s_w[2][4][HH];                   // per-wave scan transforms
    __shared__ __align__(16) float4 s_lut[HH];         // layer-0 (a0,b0,a1,b1) per h
    __shared__ float s_pb[3 * HH];                     // bz1 | bh1 | wo
    __shared__ unsigned s_xb[2 * (NCSEG + NWARM)];     // bit-packed x segment

    const float* xrow = x + (size_t)b * LL;

    // ---- stage x bits via ballot (x is exactly {0.0, 1.0}) ----
    for (int g = tg; g < NC; g += 4) {
        const int t = tstart + g * 64 + lane;
        const float xval = pm ? xrow[p[t]] : xrow[t];
        const unsigned long long m = __ballot(xval != 0.0f);
        if (lane == 0) {
            s_xb[2 * g]     = (unsigned)m;
            s_xb[2 * g + 1] = (unsigned)(m >> 32);
        }
    }

    // ---- stage layer-0 LUT + layer-1 biases + wo into LDS ----
    if (seg == 0) {
        const float z0v = rcp_(1.0f + __expf(-bz0[hidx]));
        const float z1v = rcp_(1.0f + __expf(-(wz0[hidx] + bz0[hidx])));
        float4 lt;
        lt.x = 1.0f - z0v;
        lt.y = z0v * bh0[hidx];
        lt.z = 1.0f - z1v;
        lt.w = z1v * (wh0[hidx] + bh0[hidx]);
        s_lut[hidx] = lt;
        s_pb[hidx]          = bz1[hidx];
        s_pb[HH + hidx]     = bh1[hidx];
        s_pb[2 * HH + hidx] = wo[hidx];
    }

    // ---- layer-1 weight B-fragments, RNE bf16 (persistent: 64 VGPRs) ----
    bf16x8 wfz[2][4], wfh[2][4];
    for (int ks = 0; ks < 2; ++ks) {
        for (int ht = 0; ht < 4; ++ht) {
            #pragma unroll
            for (int j = 0; j < 8; ++j) {
                const int kk = ks * 32 + q * 8 + j;
                const int hh = ht * 16 + n;
                wfz[ks][ht][j] = f2bf_rne(wz1[kk * HH + hh]);
                wfh[ks][ht][j] = f2bf_rne(wh1[kk * HH + hh]);
            }
        }
    }
    const float bo = bov[0];

    float carry0 = 0.0f;
    float carry1[4] = {0.0f, 0.0f, 0.0f, 0.0f};
    f32x4 ga[4], gb[4];
    float Aqe[4], Bqe[4];
    float lsum = 0.0f, lsum2 = 0.0f;
    float* outp = out + (pm ? 1 : 0);
    const int t0 = tg * 16;
    const int col0 = hidx ^ ((seg & 1) << 4);   // s_h col swizzle (write side)

    __syncthreads();   // staging done

    // G2: apply layer-1 scan for local chunk cm, fused output projection.
    // Stores only for real (non-warm-up) chunks.
    auto g2_step = [&](int cm) {
        const int buf = cm & 1;
        float Acm[4] = {1,1,1,1}, Bcm[4] = {0,0,0,0};
        float Ap[4], Bp[4];
        #pragma unroll
        for (int w = 0; w < 4; ++w) {
            #pragma unroll
            for (int ht = 0; ht < 4; ++ht) {
                if (w == tg) { Ap[ht] = Acm[ht]; Bp[ht] = Bcm[ht]; }
                const float2 ab = s_w[buf][w][ht * 16 + n];
                Bcm[ht] = fmaf(ab.x, Bcm[ht], ab.y);
                Acm[ht] *= ab.x;
            }
        }
        float vo[4] = {0,0,0,0};
        #pragma unroll
        for (int ht = 0; ht < 4; ++ht) {
            const float rwoh = s_pb[2 * HH + ht * 16 + n];
            float cc = fmaf(Aqe[ht], fmaf(Ap[ht], carry1[ht], Bp[ht]), Bqe[ht]);
            #pragma unroll
            for (int r = 0; r < 4; ++r) {
                cc = fmaf(ga[ht][r], cc, gb[ht][r]);
                vo[r] = fmaf(cc, rwoh, vo[r]);
            }
            carry1[ht] = fmaf(Acm[ht], carry1[ht], Bcm[ht]);
        }
        #pragma unroll
        for (int r = 0; r < 4; ++r) {
            vo[r] += rshr<1>(vo[r]);
            vo[r] += rshr<2>(vo[r]);
            vo[r] += rshr<4>(vo[r]);
            vo[r] += rshr<8>(vo[r]);
        }
        if (n == 15 && cm >= nwarm) {
            const int gout = z * NCSEG + (cm - nwarm);   // global chunk
            #pragma unroll
            for (int r = 0; r < 4; ++r) {
                const float v = vo[r] + bo;
                outp[((size_t)b * LL + gout * TT + t0 + q * 4 + r) * 2] = v;
                lsum += v;
                lsum2 = fmaf(v, v, lsum2);
            }
        }
    };

    // ---- prologue: P1(0) -> s_h buf 0 ----
    {
        const unsigned bits = s_xb[seg >> 1] >> ((seg & 1) * 16);
        const float4 lt = s_lut[hidx];
        p1_scan(bits, lt.x, lt.y, lt.z, lt.w, seg, col0, carry0, s_h);
    }
    __syncthreads();

    for (int c = 0; c < NC; ++c) {
        // ---- G2(c-1): previous chunk's gates still in registers ----
        if (c > 0) g2_step(c - 1);

        // ---- G1(c): MFMA + gates + per-wave scan transforms ----
        {
            #pragma unroll
            for (int ht = 0; ht < 4; ++ht) {
                const float bz = s_pb[ht * 16 + n];
                const float bh = s_pb[HH + ht * 16 + n];
                ga[ht] = (f32x4){bz, bz, bz, bz};
                gb[ht] = (f32x4){bh, bh, bh, bh};
            }
            const float* shR = s_h + (c & 1) * (TT * SS);
            const int qs = q ^ ((tg & 1) << 1);   // undo s_h col swizzle (t>>4 == tg)
            #pragma unroll
            for (int ks = 0; ks < 2; ++ks) {
                const float* ap = &shR[(t0 + n) * SS + ks * 32 + qs * 8];
                const float4 av0 = *(const float4*)ap;
                const float4 av1 = *(const float4*)(ap + 4);
                const float af[8] = {av0.x, av0.y, av0.z, av0.w,
                                     av1.x, av1.y, av1.z, av1.w};
                bf16x8 ahi;
                #pragma unroll
                for (int j = 0; j < 8; ++j) ahi[j] = f2bf_rne(af[j]);
                #pragma unroll
                for (int ht = 0; ht < 4; ++ht) {
                    ga[ht] = __builtin_amdgcn_mfma_f32_16x16x32_bf16(ahi, wfz[ks][ht], ga[ht], 0, 0, 0);
                    gb[ht] = __builtin_amdgcn_mfma_f32_16x16x32_bf16(ahi, wfh[ks][ht], gb[ht], 0, 0, 0);
                }
            }
            // gates: a = 1-sigmoid(v) = rcp(1+exp(v)); b = htl - a*htl
            #pragma unroll
            for (int ht = 0; ht < 4; ++ht) {
                #pragma unroll
                for (int r = 0; r < 4; ++r) {
                    const float v   = ga[ht][r];
                    const float a   = rcp_(1.0f + __expf(v));
                    const float htl = gb[ht][r];
                    ga[ht][r] = a;
                    gb[ht][r] = fmaf(-a, htl, htl);
                }
            }
            // compose own 4 r-steps per ht
            float Aq[4], Bq[4];
            #pragma unroll
            for (int ht = 0; ht < 4; ++ht) {
                float A = 1.0f, B = 0.0f;
                #pragma unroll
                for (int r = 0; r < 4; ++r) {
                    B = fmaf(ga[ht][r], B, gb[ht][r]);
                    A = A * ga[ht][r];
                }
                Aq[ht] = A; Bq[ht] = B;
            }
            // inclusive Hillis-Steele over q (lane strides 16, 32)
            #pragma unroll
            for (int ht = 0; ht < 4; ++ht) {
                const float Au = __shfl_up(Aq[ht], 16), Bu = __shfl_up(Bq[ht], 16);
                if (q >= 1) { const float Ac = Aq[ht]; Aq[ht] = Ac * Au; Bq[ht] = fmaf(Ac, Bu, Bq[ht]); }
            }
            #pragma unroll
            for (int ht = 0; ht < 4; ++ht) {
                const float Au = __shfl_up(Aq[ht], 32), Bu = __shfl_up(Bq[ht], 32);
                if (q >= 2) { const float Ac = Aq[ht]; Aq[ht] = Ac * Au; Bq[ht] = fmaf(Ac, Bu, Bq[ht]); }
            }
            // exclusive-q transforms (persist to G2)
            #pragma unroll
            for (int ht = 0; ht < 4; ++ht) {
                const float Ae = __shfl_up(Aq[ht], 16), Be = __shfl_up(Bq[ht], 16);
                Aqe[ht] = (q == 0) ? 1.0f : Ae;
                Bqe[ht] = (q == 0) ? 0.0f : Be;
            }
            // q==3 lanes publish the wave-block inclusive transform
            if (q == 3) {
                #pragma unroll
                for (int ht = 0; ht < 4; ++ht)
                    s_w[c & 1][tg][ht * 16 + n] = make_float2(Aq[ht], Bq[ht]);
            }
        }

        // ---- P1(c+1) -> other s_h buffer ----
        if (c + 1 < NC) {
            const int cp1 = c + 1;
            const unsigned bits = s_xb[2 * cp1 + (seg >> 1)] >> ((seg & 1) * 16);
            const float4 lt = s_lut[hidx];
            p1_scan(bits, lt.x, lt.y, lt.z, lt.w, seg, col0, carry0,
                    s_h + (cp1 & 1) * (TT * SS));
        }
        __syncthreads();
    }

    // ---- G2 for the last chunk ----
    g2_step(NC - 1);

    // ---- block partial (sum, sumsq) -> ws slot (plain stores) ----
    #pragma unroll
    for (int o = 32; o; o >>= 1) {
        lsum  += __shfl_down(lsum, o);
        lsum2 += __shfl_down(lsum2, o);
    }
    __syncthreads();                     // safe to reuse s_lut as scratch
    float* s_red = (float*)s_lut;
    if (lane == 0) { s_red[tg] = lsum; s_red[4 + tg] = lsum2; }
    __syncthreads();
    if (tid == 0) {
        const int gb2 = (b * 2 + (pm ? 1 : 0)) * 2 + z;
        ws[2 * gb2]     = s_red[0] + s_red[1] + s_red[2] + s_red[3];
        ws[2 * gb2 + 1] = s_red[4] + s_red[5] + s_red[6] + s_red[7];
    }
}

// Fold the 1024 block-partials (redundantly per block), normalize in-place.
__global__ void normalize_k(float* __restrict__ out, const float* __restrict__ ws)
{
    __shared__ float s_red[8];
    float s = 0.0f, s2 = 0.0f;
    for (int i = threadIdx.x; i < 4 * BB; i += 256) {
        s  += ws[2 * i];
        s2 += ws[2 * i + 1];
    }
    #pragma unroll
    for (int o = 32; o; o >>= 1) {
        s  += __shfl_down(s, o);
        s2 += __shfl_down(s2, o);
    }
    const int wid = threadIdx.x >> 6;
    if ((threadIdx.x & 63) == 0) { s_red[wid] = s; s_red[4 + wid] = s2; }
    __syncthreads();
    const float tot  = s_red[0] + s_red[1] + s_red[2] + s_red[3];
    const float tot2 = s_red[4] + s_red[5] + s_red[6] + s_red[7];
    const float N    = (float)NTOT;
    const float mean = tot / N;
    const float var  = (tot2 - N * mean * mean) / (N - 1.0f);
    const float inv  = rsqrtf(var);

    const int i = blockIdx.x * blockDim.x + threadIdx.x;   // exactly NTOT/4 threads
    float4* o4 = (float4*)out;
    float4 v = o4[i];
    v.x = (v.x - mean) * inv;
    v.y = (v.y - mean) * inv;
    v.z = (v.z - mean) * inv;
    v.w = (v.w - mean) * inv;
    o4[i] = v;
}

extern "C" void kernel_launch(void* const* d_in, const int* in_sizes, int n_in,
                              void* d_out, int out_size, void* d_ws, size_t ws_size,
                              hipStream_t stream)
{
    (void)in_sizes; (void)n_in; (void)out_size; (void)ws_size;
    const float* x = (const float*)d_in[0];
    const int*   p = (const int*)d_in[1];
    float* out = (float*)d_out;
    float* ws  = (float*)d_ws;

    dim3 grid(BB, 2, 2);
    gru_fused<<<grid, 256, 0, stream>>>(
        x, p,
        (const float*)d_in[2],  (const float*)d_in[3],
        (const float*)d_in[4],  (const float*)d_in[5],
        (const float*)d_in[6],  (const float*)d_in[7],
        (const float*)d_in[8],  (const float*)d_in[9],
        (const float*)d_in[10], (const float*)d_in[11],
        (const float*)d_in[12], (const float*)d_in[13],
        (const float*)d_in[14], (const float*)d_in[15],
        (const float*)d_in[16], (const float*)d_in[17],
        (const float*)d_in[18], (const float*)d_in[19],
        (const float*)d_in[20], (const float*)d_in[21],
        out, ws);

    normalize_k<<<NTOT / 4 / 256, 256, 0, stream>>>(out, ws);
}

// Round 10
// 232.661 us; speedup vs baseline: 1.0167x; 1.0167x over previous
//
#include <hip/hip_runtime.h>

#define BB 256
#define LL 2048
#define HH 64
#define TT 64             // chunk length along L
#define SS 68             // padded LDS row stride (floats)
#define NSEG 2            // L split across blocks
#define SEGL (LL / NSEG)  // 1024
#define NCSEG (SEGL / TT) // 16 real chunks per segment
#define NWARM 2           // warm-up chunks (128 steps) for z>0; carry error ~<=1e-4
#define NTOT (BB * LL * 2)

typedef __attribute__((ext_vector_type(8))) short bf16x8;
typedef __attribute__((ext_vector_type(4))) float f32x4;

__device__ __forceinline__ float rcp_(float x) { return __builtin_amdgcn_rcpf(x); }

// RNE fp32->bf16
__device__ __forceinline__ short f2bf_rne(float f) {
    union { float f; unsigned u; } v; v.f = f;
    unsigned r = v.u + 0x7fff + ((v.u >> 16) & 1);
    return (short)(r >> 16);
}

// DPP quad_perm: 0x90 = shift-up-1, 0x44 = shift-up-2, 0xFF = bcast lane3 of quad.
template<int CTRL>
__device__ __forceinline__ float qdpp(float x) {
    union { float f; int i; } u, r;
    u.f = x;
    r.i = __builtin_amdgcn_update_dpp(0, u.i, CTRL, 0xF, 0xF, false);
    return r.f;
}

// DPP row_shr:D, zero bound: lane i gets lane i-D within its 16-lane row.
template<int D>
__device__ __forceinline__ float rshr(float x) {
    union { float f; int i; } u, r;
    u.f = x;
    r.i = __builtin_amdgcn_update_dpp(0, u.i, 0x110 | D, 0xF, 0xF, true);
    return r.f;
}

// Layer-0 gates from 16-bit mask + LUT, 64-step scan (16 local + quad DPP scan),
// writes h0 to sh with the bit4 column swizzle. Gates recomputed from bits in the
// apply pass (no ai/bi arrays -> low register pressure).
__device__ __forceinline__ void p1_scan(unsigned bits,
                                        float a0v, float b0v, float a1v, float b1v,
                                        int seg, int col0, float& carry, float* sh)
{
    float A = 1.0f, Bv = 0.0f;
    #pragma unroll
    for (int i = 0; i < 16; ++i) {
        const bool on = (bits >> i) & 1u;
        const float ai = on ? a1v : a0v;
        const float bi = on ? b1v : b0v;
        A  = A * ai;
        Bv = fmaf(Bv, ai, bi);
    }
    {
        const float Au = qdpp<0x90>(A), Bu = qdpp<0x90>(Bv);
        if (seg >= 1) { const float Ac = A; A = Au * Ac; Bv = fmaf(Bu, Ac, Bv); }
        const float Au2 = qdpp<0x44>(A), Bu2 = qdpp<0x44>(Bv);
        if (seg >= 2) { const float Ac = A; A = Au2 * Ac; Bv = fmaf(Bu2, Ac, Bv); }
    }
    float Ae = qdpp<0x90>(A), Be = qdpp<0x90>(Bv);
    if (seg == 0) { Ae = 1.0f; Be = 0.0f; }
    float cc = fmaf(Ae, carry, Be);
    #pragma unroll
    for (int i = 0; i < 16; ++i) {
        const bool on = (bits >> i) & 1u;
        const float ai = on ? a1v : a0v;
        const float bi = on ? b1v : b0v;
        cc = fmaf(ai, cc, bi);
        sh[(seg * 16 + i) * SS + col0] = cc;
    }
    carry = qdpp<0xFF>(cc);   // broadcast quad lane-3 final state
}

// __launch_bounds__(256, 4): min 4 waves/EU -> 128-VGPR cap, 4 blocks/CU.
// (round 9's amdgpu_waves_per_eu(4,4) made the allocator target 64 VGPRs and
// spill 100+ MB/launch — do not use it)
__global__ void __launch_bounds__(256, 4)
gru_fused(const float* __restrict__ x, const int* __restrict__ p,
               const float* __restrict__ w1z0, const float* __restrict__ b1z0,
               const float* __restrict__ w1h0, const float* __restrict__ b1h0,
               const float* __restrict__ w1z1, const float* __restrict__ b1z1,
               const float* __restrict__ w1h1, const float* __restrict__ b1h1,
               const float* __restrict__ w1o,  const float* __restrict__ b1o,
               const float* __restrict__ w2z0, const float* __restrict__ b2z0,
               const float* __restrict__ w2h0, const float* __restrict__ b2h0,
               const float* __restrict__ w2z1, const float* __restrict__ b2z1,
               const float* __restrict__ w2h1, const float* __restrict__ b2h1,
               const float* __restrict__ w2o,  const float* __restrict__ b2o,
               float* __restrict__ out, float* __restrict__ ws)
{
    const int  b  = blockIdx.x;
    const bool pm = (blockIdx.y != 0);
    const int  z  = blockIdx.z;                 // L-segment index
    const int nwarm  = z ? NWARM : 0;
    const int NC     = NCSEG + nwarm;           // local chunks incl. warm-up
    const int tstart = z * SEGL - nwarm * TT;   // 0 or 896

    const float* wz0 = pm ? w2z0 : w1z0;
    const float* bz0 = pm ? b2z0 : b1z0;
    const float* wh0 = pm ? w2h0 : w1h0;
    const float* bh0 = pm ? b2h0 : b1h0;
    const float* wz1 = pm ? w2z1 : w1z1;
    const float* bz1 = pm ? b2z1 : b1z1;
    const float* wh1 = pm ? w2h1 : w1h1;
    const float* bh1 = pm ? b2h1 : b1h1;
    const float* wo  = pm ? w2o  : w1o;
    const float* bov = pm ? b2o  : b1o;

    const int tid  = threadIdx.x;
    const int lane = tid & 63;
    const int tg   = tid >> 6;          // wave id; owns t-block [16*tg, 16*tg+16)
    const int q    = lane >> 4;         // MFMA quad
    const int n    = lane & 15;         // MFMA col (h low bits)
    const int seg  = lane & 3;          // P1 segment
    const int hidx = (tg << 4) | (lane >> 2);

    __shared__ __align__(16) float s_h[2 * TT * SS];   // double-buffered h0 (swizzled)
    __shared__ float2 s_w[2][4][HH];                   // per-wave scan transforms
    __shared__ __align__(16) float4 s_lut[HH];         // layer-0 (a0,b0,a1,b1) per h
    __shared__ float s_pb[3 * HH];                     // bz1 | bh1 | wo
    __shared__ unsigned s_xb[2 * (NCSEG + NWARM)];     // bit-packed x segment

    const float* xrow = x + (size_t)b * LL;

    // ---- stage x bits via ballot (x is exactly {0.0, 1.0}) ----
    for (int g = tg; g < NC; g += 4) {
        const int t = tstart + g * 64 + lane;
        const float xval = pm ? xrow[p[t]] : xrow[t];
        const unsigned long long m = __ballot(xval != 0.0f);
        if (lane == 0) {
            s_xb[2 * g]     = (unsigned)m;
            s_xb[2 * g + 1] = (unsigned)(m >> 32);
        }
    }

    // ---- stage layer-0 LUT + layer-1 biases + wo into LDS ----
    if (seg == 0) {
        const float z0v = rcp_(1.0f + __expf(-bz0[hidx]));
        const float z1v = rcp_(1.0f + __expf(-(wz0[hidx] + bz0[hidx])));
        float4 lt;
        lt.x = 1.0f - z0v;
        lt.y = z0v * bh0[hidx];
        lt.z = 1.0f - z1v;
        lt.w = z1v * (wh0[hidx] + bh0[hidx]);
        s_lut[hidx] = lt;
        s_pb[hidx]          = bz1[hidx];
        s_pb[HH + hidx]     = bh1[hidx];
        s_pb[2 * HH + hidx] = wo[hidx];
    }

    // ---- layer-1 weight B-fragments, RNE bf16 (persistent: 64 VGPRs) ----
    bf16x8 wfz[2][4], wfh[2][4];
    for (int ks = 0; ks < 2; ++ks) {
        for (int ht = 0; ht < 4; ++ht) {
            #pragma unroll
            for (int j = 0; j < 8; ++j) {
                const int kk = ks * 32 + q * 8 + j;
                const int hh = ht * 16 + n;
                wfz[ks][ht][j] = f2bf_rne(wz1[kk * HH + hh]);
                wfh[ks][ht][j] = f2bf_rne(wh1[kk * HH + hh]);
            }
        }
    }
    const float bo = bov[0];

    float carry0 = 0.0f;
    float carry1[4] = {0.0f, 0.0f, 0.0f, 0.0f};
    f32x4 ga[4], gb[4];     // layer-1 gates; Aqe/Bqe pre-folded into ga/gb[0]
    float lsum = 0.0f, lsum2 = 0.0f;
    float* outp = out + (pm ? 1 : 0);
    const int t0 = tg * 16;
    const int col0 = hidx ^ ((seg & 1) << 4);   // s_h col swizzle (write side)

    __syncthreads();   // staging done

    // G2: apply layer-1 scan for local chunk cm, fused output projection.
    // Stores only for real (non-warm-up) chunks.
    auto g2_step = [&](int cm) {
        const int buf = cm & 1;
        float Acm[4] = {1,1,1,1}, Bcm[4] = {0,0,0,0};
        float Ap[4], Bp[4];
        #pragma unroll
        for (int w = 0; w < 4; ++w) {
            #pragma unroll
            for (int ht = 0; ht < 4; ++ht) {
                if (w == tg) { Ap[ht] = Acm[ht]; Bp[ht] = Bcm[ht]; }
                const float2 ab = s_w[buf][w][ht * 16 + n];
                Bcm[ht] = fmaf(ab.x, Bcm[ht], ab.y);
                Acm[ht] *= ab.x;
            }
        }
        float vo[4] = {0,0,0,0};
        #pragma unroll
        for (int ht = 0; ht < 4; ++ht) {
            const float rwoh = s_pb[2 * HH + ht * 16 + n];
            float cc = fmaf(Ap[ht], carry1[ht], Bp[ht]);   // Aqe/Bqe folded into gates
            #pragma unroll
            for (int r = 0; r < 4; ++r) {
                cc = fmaf(ga[ht][r], cc, gb[ht][r]);
                vo[r] = fmaf(cc, rwoh, vo[r]);
            }
            carry1[ht] = fmaf(Acm[ht], carry1[ht], Bcm[ht]);
        }
        #pragma unroll
        for (int r = 0; r < 4; ++r) {
            vo[r] += rshr<1>(vo[r]);
            vo[r] += rshr<2>(vo[r]);
            vo[r] += rshr<4>(vo[r]);
            vo[r] += rshr<8>(vo[r]);
        }
        if (n == 15 && cm >= nwarm) {
            const int gout = z * NCSEG + (cm - nwarm);   // global chunk
            #pragma unroll
            for (int r = 0; r < 4; ++r) {
                const float v = vo[r] + bo;
                outp[((size_t)b * LL + gout * TT + t0 + q * 4 + r) * 2] = v;
                lsum += v;
                lsum2 = fmaf(v, v, lsum2);
            }
        }
    };

    // ---- prologue: P1(0) -> s_h buf 0 ----
    {
        const unsigned bits = s_xb[seg >> 1] >> ((seg & 1) * 16);
        const float4 lt = s_lut[hidx];
        p1_scan(bits, lt.x, lt.y, lt.z, lt.w, seg, col0, carry0, s_h);
    }
    __syncthreads();

    for (int c = 0; c < NC; ++c) {
        // ---- G2(c-1): previous chunk's gates still in registers ----
        if (c > 0) g2_step(c - 1);

        // ---- G1(c): MFMA + gates + per-wave scan transforms ----
        {
            #pragma unroll
            for (int ht = 0; ht < 4; ++ht) {
                const float bz = s_pb[ht * 16 + n];
                const float bh = s_pb[HH + ht * 16 + n];
                ga[ht] = (f32x4){bz, bz, bz, bz};
                gb[ht] = (f32x4){bh, bh, bh, bh};
            }
            const float* shR = s_h + (c & 1) * (TT * SS);
            const int qs = q ^ ((tg & 1) << 1);   // undo s_h col swizzle (t>>4 == tg)
            #pragma unroll
            for (int ks = 0; ks < 2; ++ks) {
                const float* ap = &shR[(t0 + n) * SS + ks * 32 + qs * 8];
                const float4 av0 = *(const float4*)ap;
                const float4 av1 = *(const float4*)(ap + 4);
                const float af[8] = {av0.x, av0.y, av0.z, av0.w,
                                     av1.x, av1.y, av1.z, av1.w};
                bf16x8 ahi;
                #pragma unroll
                for (int j = 0; j < 8; ++j) ahi[j] = f2bf_rne(af[j]);
                #pragma unroll
                for (int ht = 0; ht < 4; ++ht) {
                    ga[ht] = __builtin_amdgcn_mfma_f32_16x16x32_bf16(ahi, wfz[ks][ht], ga[ht], 0, 0, 0);
                    gb[ht] = __builtin_amdgcn_mfma_f32_16x16x32_bf16(ahi, wfh[ks][ht], gb[ht], 0, 0, 0);
                }
            }
            // gates: a = 1-sigmoid(v) = rcp(1+exp(v)); b = htl - a*htl
            #pragma unroll
            for (int ht = 0; ht < 4; ++ht) {
                #pragma unroll
                for (int r = 0; r < 4; ++r) {
                    const float v   = ga[ht][r];
                    const float a   = rcp_(1.0f + __expf(v));
                    const float htl = gb[ht][r];
                    ga[ht][r] = a;
                    gb[ht][r] = fmaf(-a, htl, htl);
                }
            }
            // compose own 4 r-steps per ht
            float Aq[4], Bq[4];
            #pragma unroll
            for (int ht = 0; ht < 4; ++ht) {
                float A = 1.0f, B = 0.0f;
                #pragma unroll
                for (int r = 0; r < 4; ++r) {
                    B = fmaf(ga[ht][r], B, gb[ht][r]);
                    A = A * ga[ht][r];
                }
                Aq[ht] = A; Bq[ht] = B;
            }
            // inclusive Hillis-Steele over q (lane strides 16, 32)
            #pragma unroll
            for (int ht = 0; ht < 4; ++ht) {
                const float Au = __shfl_up(Aq[ht], 16), Bu = __shfl_up(Bq[ht], 16);
                if (q >= 1) { const float Ac = Aq[ht]; Aq[ht] = Ac * Au; Bq[ht] = fmaf(Ac, Bu, Bq[ht]); }
            }
            #pragma unroll
            for (int ht = 0; ht < 4; ++ht) {
                const float Au = __shfl_up(Aq[ht], 32), Bu = __shfl_up(Bq[ht], 32);
                if (q >= 2) { const float Ac = Aq[ht]; Aq[ht] = Ac * Au; Bq[ht] = fmaf(Ac, Bu, Bq[ht]); }
            }
            // q==3 lanes publish the wave-block inclusive transform
            if (q == 3) {
                #pragma unroll
                for (int ht = 0; ht < 4; ++ht)
                    s_w[c & 1][tg][ht * 16 + n] = make_float2(Aq[ht], Bq[ht]);
            }
            // fold exclusive-q transforms into first gate pair (exact):
            // cc_new = ga0*(Aqe*cc + Bqe) + gb0 = (ga0*Aqe)*cc + (ga0*Bqe + gb0)
            #pragma unroll
            for (int ht = 0; ht < 4; ++ht) {
                const float Ae0 = __shfl_up(Aq[ht], 16), Be0 = __shfl_up(Bq[ht], 16);
                const float Aqe = (q == 0) ? 1.0f : Ae0;
                const float Bqe = (q == 0) ? 0.0f : Be0;
                gb[ht][0] = fmaf(ga[ht][0], Bqe, gb[ht][0]);
                ga[ht][0] = ga[ht][0] * Aqe;
            }
        }

        // ---- P1(c+1) -> other s_h buffer ----
        if (c + 1 < NC) {
            const int cp1 = c + 1;
            const unsigned bits = s_xb[2 * cp1 + (seg >> 1)] >> ((seg & 1) * 16);
            const float4 lt = s_lut[hidx];
            p1_scan(bits, lt.x, lt.y, lt.z, lt.w, seg, col0, carry0,
                    s_h + (cp1 & 1) * (TT * SS));
        }
        __syncthreads();
    }

    // ---- G2 for the last chunk ----
    g2_step(NC - 1);

    // ---- block partial (sum, sumsq) -> ws slot (plain stores) ----
    #pragma unroll
    for (int o = 32; o; o >>= 1) {
        lsum  += __shfl_down(lsum, o);
        lsum2 += __shfl_down(lsum2, o);
    }
    __syncthreads();                     // safe to reuse s_lut as scratch
    float* s_red = (float*)s_lut;
    if (lane == 0) { s_red[tg] = lsum; s_red[4 + tg] = lsum2; }
    __syncthreads();
    if (tid == 0) {
        const int gb2 = (b * 2 + (pm ? 1 : 0)) * 2 + z;
        ws[2 * gb2]     = s_red[0] + s_red[1] + s_red[2] + s_red[3];
        ws[2 * gb2 + 1] = s_red[4] + s_red[5] + s_red[6] + s_red[7];
    }
}

// Fold the 1024 block-partials (redundantly per block), normalize in-place.
__global__ void normalize_k(float* __restrict__ out, const float* __restrict__ ws)
{
    __shared__ float s_red[8];
    float s = 0.0f, s2 = 0.0f;
    for (int i = threadIdx.x; i < 4 * BB; i += 256) {
        s  += ws[2 * i];
        s2 += ws[2 * i + 1];
    }
    #pragma unroll
    for (int o = 32; o; o >>= 1) {
        s  += __shfl_down(s, o);
        s2 += __shfl_down(s2, o);
    }
    const int wid = threadIdx.x >> 6;
    if ((threadIdx.x & 63) == 0) { s_red[wid] = s; s_red[4 + wid] = s2; }
    __syncthreads();
    const float tot  = s_red[0] + s_red[1] + s_red[2] + s_red[3];
    const float tot2 = s_red[4] + s_red[5] + s_red[6] + s_red[7];
    const float N    = (float)NTOT;
    const float mean = tot / N;
    const float var  = (tot2 - N * mean * mean) / (N - 1.0f);
    const float inv  = rsqrtf(var);

    const int i = blockIdx.x * blockDim.x + threadIdx.x;   // exactly NTOT/4 threads
    float4* o4 = (float4*)out;
    float4 v = o4[i];
    v.x = (v.x - mean) * inv;
    v.y = (v.y - mean) * inv;
    v.z = (v.z - mean) * inv;
    v.w = (v.w - mean) * inv;
    o4[i] = v;
}

extern "C" void kernel_launch(void* const* d_in, const int* in_sizes, int n_in,
                              void* d_out, int out_size, void* d_ws, size_t ws_size,
                              hipStream_t stream)
{
    (void)in_sizes; (void)n_in; (void)out_size; (void)ws_size;
    const float* x = (const float*)d_in[0];
    const int*   p = (const int*)d_in[1];
    float* out = (float*)d_out;
    float* ws  = (float*)d_ws;

    dim3 grid(BB, 2, 2);
    gru_fused<<<grid, 256, 0, stream>>>(
        x, p,
        (const float*)d_in[2],  (const float*)d_in[3],
        (const float*)d_in[4],  (const float*)d_in[5],
        (const float*)d_in[6],  (const float*)d_in[7],
        (const float*)d_in[8],  (const float*)d_in[9],
        (const float*)d_in[10], (const float*)d_in[11],
        (const float*)d_in[12], (const float*)d_in[13],
        (const float*)d_in[14], (const float*)d_in[15],
        (const float*)d_in[16], (const float*)d_in[17],
        (const float*)d_in[18], (const float*)d_in[19],
        (const float*)d_in[20], (const float*)d_in[21],
        out, ws);

    normalize_k<<<NTOT / 4 / 256, 256, 0, stream>>>(out, ws);
}

// Round 11
// 186.941 us; speedup vs baseline: 1.2654x; 1.2446x over previous
//
#include <hip/hip_runtime.h>

#define BB 256
#define LL 2048
#define HH 64
#define TT 64             // chunk length along L
#define SS 68             // s_h padded row stride (floats); 272 B, 16-B aligned
#define WST 68            // weight LDS row stride (ushorts); 136 B, 8-B aligned
#define NSEG 2            // L split across blocks
#define SEGL (LL / NSEG)  // 1024
#define NCSEG (SEGL / TT) // 16 real chunks per segment
#define NWARM 2           // warm-up chunks for z>0; carry error ~<=1e-4
#define NTOT (BB * LL * 2)

typedef __attribute__((ext_vector_type(8))) short bf16x8;
typedef __attribute__((ext_vector_type(4))) float f32x4;

__device__ __forceinline__ float rcp_(float x) { return __builtin_amdgcn_rcpf(x); }

// RNE fp32->bf16
__device__ __forceinline__ short f2bf_rne(float f) {
    union { float f; unsigned u; } v; v.f = f;
    unsigned r = v.u + 0x7fff + ((v.u >> 16) & 1);
    return (short)(r >> 16);
}

// 16-B fragment from 8-B-aligned LDS (two b64 reads; stride 68 ushorts is not 16-B aligned)
__device__ __forceinline__ bf16x8 ld_w8(const unsigned short* p) {
    union { bf16x8 v; unsigned long long q[2]; } u;
    u.q[0] = *(const unsigned long long*)p;
    u.q[1] = *(const unsigned long long*)(p + 4);
    return u.v;
}

// DPP quad_perm: 0x90 = shift-up-1, 0x44 = shift-up-2, 0xFF = bcast lane3 of quad.
template<int CTRL>
__device__ __forceinline__ float qdpp(float x) {
    union { float f; int i; } u, r;
    u.f = x;
    r.i = __builtin_amdgcn_update_dpp(0, u.i, CTRL, 0xF, 0xF, false);
    return r.f;
}

// DPP row_shr:D, zero bound: lane i gets lane i-D within its 16-lane row.
template<int D>
__device__ __forceinline__ float rshr(float x) {
    union { float f; int i; } u, r;
    u.f = x;
    r.i = __builtin_amdgcn_update_dpp(0, u.i, 0x110 | D, 0xF, 0xF, true);
    return r.f;
}

// Layer-0 gates from 16-bit mask + LUT, 64-step scan (16 local + quad DPP scan),
// writes h0 to sh with the bit4 column swizzle.
__device__ __forceinline__ void p1_scan(unsigned bits,
                                        float a0v, float b0v, float a1v, float b1v,
                                        int seg, int col0, float& carry, float* sh)
{
    float A = 1.0f, Bv = 0.0f;
    #pragma unroll
    for (int i = 0; i < 16; ++i) {
        const bool on = (bits >> i) & 1u;
        const float ai = on ? a1v : a0v;
        const float bi = on ? b1v : b0v;
        A  = A * ai;
        Bv = fmaf(Bv, ai, bi);
    }
    {
        const float Au = qdpp<0x90>(A), Bu = qdpp<0x90>(Bv);
        if (seg >= 1) { const float Ac = A; A = Au * Ac; Bv = fmaf(Bu, Ac, Bv); }
        const float Au2 = qdpp<0x44>(A), Bu2 = qdpp<0x44>(Bv);
        if (seg >= 2) { const float Ac = A; A = Au2 * Ac; Bv = fmaf(Bu2, Ac, Bv); }
    }
    float Ae = qdpp<0x90>(A), Be = qdpp<0x90>(Bv);
    if (seg == 0) { Ae = 1.0f; Be = 0.0f; }
    float cc = fmaf(Ae, carry, Be);
    #pragma unroll
    for (int i = 0; i < 16; ++i) {
        const bool on = (bits >> i) & 1u;
        const float ai = on ? a1v : a0v;
        const float bi = on ? b1v : b0v;
        cc = fmaf(ai, cc, bi);
        sh[(seg * 16 + i) * SS + col0] = cc;
    }
    carry = qdpp<0xFF>(cc);   // broadcast quad lane-3 final state
}

// min 4 waves/EU -> 128-reg/wave budget; demand now ~70-85 arch + 32 acc (weights
// moved to LDS) so it must fit without spill. Tripwire: WRITE_SIZE ~5 MB.
__global__ void __launch_bounds__(256, 4)
gru_fused(const float* __restrict__ x, const int* __restrict__ p,
               const float* __restrict__ w1z0, const float* __restrict__ b1z0,
               const float* __restrict__ w1h0, const float* __restrict__ b1h0,
               const float* __restrict__ w1z1, const float* __restrict__ b1z1,
               const float* __restrict__ w1h1, const float* __restrict__ b1h1,
               const float* __restrict__ w1o,  const float* __restrict__ b1o,
               const float* __restrict__ w2z0, const float* __restrict__ b2z0,
               const float* __restrict__ w2h0, const float* __restrict__ b2h0,
               const float* __restrict__ w2z1, const float* __restrict__ b2z1,
               const float* __restrict__ w2h1, const float* __restrict__ b2h1,
               const float* __restrict__ w2o,  const float* __restrict__ b2o,
               float* __restrict__ out, float* __restrict__ ws)
{
    const int  b  = blockIdx.x;
    const bool pm = (blockIdx.y != 0);
    const int  z  = blockIdx.z;                 // L-segment index
    const int nwarm  = z ? NWARM : 0;
    const int NC     = NCSEG + nwarm;           // local chunks incl. warm-up
    const int tstart = z * SEGL - nwarm * TT;   // 0 or 896

    const float* wz0 = pm ? w2z0 : w1z0;
    const float* bz0 = pm ? b2z0 : b1z0;
    const float* wh0 = pm ? w2h0 : w1h0;
    const float* bh0 = pm ? b2h0 : b1h0;
    const float* wz1 = pm ? w2z1 : w1z1;
    const float* bz1 = pm ? b2z1 : b1z1;
    const float* wh1 = pm ? w2h1 : w1h1;
    const float* bh1 = pm ? b2h1 : b1h1;
    const float* wo  = pm ? w2o  : w1o;
    const float* bov = pm ? b2o  : b1o;

    const int tid  = threadIdx.x;
    const int lane = tid & 63;
    const int tg   = tid >> 6;          // wave id; owns t-block [16*tg, 16*tg+16)
    const int q    = lane >> 4;         // MFMA quad
    const int n    = lane & 15;         // MFMA col (h low bits)
    const int seg  = lane & 3;          // P1 segment
    const int hidx = (tg << 4) | (lane >> 2);

    __shared__ __align__(16) float s_h[TT * SS];          // h0, single buffer (swizzled)
    __shared__ __align__(8)  unsigned short s_wz[HH * WST]; // bf16 Wz1, [h][k] swizzled
    __shared__ __align__(8)  unsigned short s_wh[HH * WST]; // bf16 Wh1, [h][k] swizzled
    __shared__ float2 s_w[2][4][HH];                      // per-wave scan transforms
    __shared__ __align__(16) float4 s_lut[HH];            // layer-0 (a0,b0,a1,b1) per h
    __shared__ float s_pb[3 * HH];                        // bz1 | bh1 | wo
    __shared__ unsigned s_xb[2 * (NCSEG + NWARM)];        // bit-packed x segment

    const float* xrow = x + (size_t)b * LL;

    // ---- stage x bits via ballot (x is exactly {0.0, 1.0}) ----
    for (int g = tg; g < NC; g += 4) {
        const int t = tstart + g * 64 + lane;
        const float xval = pm ? xrow[p[t]] : xrow[t];
        const unsigned long long m = __ballot(xval != 0.0f);
        if (lane == 0) {
            s_xb[2 * g]     = (unsigned)m;
            s_xb[2 * g + 1] = (unsigned)(m >> 32);
        }
    }

    // ---- stage bf16 layer-1 weights: s_w*[hh][kk ^ ((hh&3)<<3)] ----
    for (int idx = tid; idx < HH * HH; idx += 256) {
        const int kk = idx >> 6, hh = idx & 63;            // src is [k][h]
        const int col = kk ^ ((hh & 3) << 3);
        s_wz[hh * WST + col] = (unsigned short)f2bf_rne(wz1[idx]);
        s_wh[hh * WST + col] = (unsigned short)f2bf_rne(wh1[idx]);
    }

    // ---- stage layer-0 LUT + layer-1 biases + wo ----
    if (seg == 0) {
        const float z0v = rcp_(1.0f + __expf(-bz0[hidx]));
        const float z1v = rcp_(1.0f + __expf(-(wz0[hidx] + bz0[hidx])));
        float4 lt;
        lt.x = 1.0f - z0v;
        lt.y = z0v * bh0[hidx];
        lt.z = 1.0f - z1v;
        lt.w = z1v * (wh0[hidx] + bh0[hidx]);
        s_lut[hidx] = lt;
        s_pb[hidx]          = bz1[hidx];
        s_pb[HH + hidx]     = bh1[hidx];
        s_pb[2 * HH + hidx] = wo[hidx];
    }
    const float bo = bov[0];

    float carry0 = 0.0f;
    float carry1[4] = {0.0f, 0.0f, 0.0f, 0.0f};
    f32x4 ga[4], gb[4];     // layer-1 gates; Aqe/Bqe pre-folded into ga/gb[0]
    float lsum = 0.0f, lsum2 = 0.0f;
    float* outp = out + (pm ? 1 : 0);
    const int t0 = tg * 16;
    const int col0 = hidx ^ ((seg & 1) << 4);   // s_h col swizzle (write side)

    __syncthreads();   // staging done

    // G2: apply layer-1 scan for local chunk cm, fused output projection.
    auto g2_step = [&](int cm) {
        const int buf = cm & 1;
        float Acm[4] = {1,1,1,1}, Bcm[4] = {0,0,0,0};
        float Ap[4], Bp[4];
        #pragma unroll
        for (int w = 0; w < 4; ++w) {
            #pragma unroll
            for (int ht = 0; ht < 4; ++ht) {
                if (w == tg) { Ap[ht] = Acm[ht]; Bp[ht] = Bcm[ht]; }
                const float2 ab = s_w[buf][w][ht * 16 + n];
                Bcm[ht] = fmaf(ab.x, Bcm[ht], ab.y);
                Acm[ht] *= ab.x;
            }
        }
        float vo[4] = {0,0,0,0};
        #pragma unroll
        for (int ht = 0; ht < 4; ++ht) {
            const float rwoh = s_pb[2 * HH + ht * 16 + n];
            float cc = fmaf(Ap[ht], carry1[ht], Bp[ht]);   // Aqe/Bqe folded into gates
            #pragma unroll
            for (int r = 0; r < 4; ++r) {
                cc = fmaf(ga[ht][r], cc, gb[ht][r]);
                vo[r] = fmaf(cc, rwoh, vo[r]);
            }
            carry1[ht] = fmaf(Acm[ht], carry1[ht], Bcm[ht]);
        }
        #pragma unroll
        for (int r = 0; r < 4; ++r) {
            vo[r] += rshr<1>(vo[r]);
            vo[r] += rshr<2>(vo[r]);
            vo[r] += rshr<4>(vo[r]);
            vo[r] += rshr<8>(vo[r]);
        }
        if (n == 15 && cm >= nwarm) {
            const int gout = z * NCSEG + (cm - nwarm);
            #pragma unroll
            for (int r = 0; r < 4; ++r) {
                const float v = vo[r] + bo;
                outp[((size_t)b * LL + gout * TT + t0 + q * 4 + r) * 2] = v;
                lsum += v;
                lsum2 = fmaf(v, v, lsum2);
            }
        }
    };

    // ---- prologue: P1(0) -> s_h ----
    {
        const unsigned bits = s_xb[seg >> 1] >> ((seg & 1) * 16);
        const float4 lt = s_lut[hidx];
        p1_scan(bits, lt.x, lt.y, lt.z, lt.w, seg, col0, carry0, s_h);
    }
    __syncthreads();

    for (int c = 0; c < NC; ++c) {
        // ---- G2(c-1): previous chunk's gates still in registers ----
        if (c > 0) g2_step(c - 1);

        // ---- G1(c): MFMA (weights from LDS) + gates + scan transforms ----
        {
            #pragma unroll
            for (int ht = 0; ht < 4; ++ht) {
                const float bz = s_pb[ht * 16 + n];
                const float bh = s_pb[HH + ht * 16 + n];
                ga[ht] = (f32x4){bz, bz, bz, bz};
                gb[ht] = (f32x4){bh, bh, bh, bh};
            }
            const int qs = q ^ ((tg & 1) << 1);   // undo s_h col swizzle (t>>4 == tg)
            #pragma unroll
            for (int ks = 0; ks < 2; ++ks) {
                const float* ap = &s_h[(t0 + n) * SS + ks * 32 + qs * 8];
                const float4 av0 = *(const float4*)ap;
                const float4 av1 = *(const float4*)(ap + 4);
                const float af[8] = {av0.x, av0.y, av0.z, av0.w,
                                     av1.x, av1.y, av1.z, av1.w};
                bf16x8 ahi;
                #pragma unroll
                for (int j = 0; j < 8; ++j) ahi[j] = f2bf_rne(af[j]);
                const int kco = (ks * 32 + q * 8) ^ ((n & 3) << 3);
                #pragma unroll
                for (int ht = 0; ht < 4; ++ht) {
                    const int base = (ht * 16 + n) * WST + kco;
                    const bf16x8 wz8 = ld_w8(s_wz + base);
                    ga[ht] = __builtin_amdgcn_mfma_f32_16x16x32_bf16(ahi, wz8, ga[ht], 0, 0, 0);
                    const bf16x8 wh8 = ld_w8(s_wh + base);
                    gb[ht] = __builtin_amdgcn_mfma_f32_16x16x32_bf16(ahi, wh8, gb[ht], 0, 0, 0);
                }
            }
            // gates: a = 1-sigmoid(v) = rcp(1+exp(v)); b = htl - a*htl
            #pragma unroll
            for (int ht = 0; ht < 4; ++ht) {
                #pragma unroll
                for (int r = 0; r < 4; ++r) {
                    const float v   = ga[ht][r];
                    const float a   = rcp_(1.0f + __expf(v));
                    const float htl = gb[ht][r];
                    ga[ht][r] = a;
                    gb[ht][r] = fmaf(-a, htl, htl);
                }
            }
            // compose own 4 r-steps per ht
            float Aq[4], Bq[4];
            #pragma unroll
            for (int ht = 0; ht < 4; ++ht) {
                float A = 1.0f, B = 0.0f;
                #pragma unroll
                for (int r = 0; r < 4; ++r) {
                    B = fmaf(ga[ht][r], B, gb[ht][r]);
                    A = A * ga[ht][r];
                }
                Aq[ht] = A; Bq[ht] = B;
            }
            // inclusive Hillis-Steele over q (lane strides 16, 32)
            #pragma unroll
            for (int ht = 0; ht < 4; ++ht) {
                const float Au = __shfl_up(Aq[ht], 16), Bu = __shfl_up(Bq[ht], 16);
                if (q >= 1) { const float Ac = Aq[ht]; Aq[ht] = Ac * Au; Bq[ht] = fmaf(Ac, Bu, Bq[ht]); }
            }
            #pragma unroll
            for (int ht = 0; ht < 4; ++ht) {
                const float Au = __shfl_up(Aq[ht], 32), Bu = __shfl_up(Bq[ht], 32);
                if (q >= 2) { const float Ac = Aq[ht]; Aq[ht] = Ac * Au; Bq[ht] = fmaf(Ac, Bu, Bq[ht]); }
            }
            // q==3 lanes publish the wave-block inclusive transform
            if (q == 3) {
                #pragma unroll
                for (int ht = 0; ht < 4; ++ht)
                    s_w[c & 1][tg][ht * 16 + n] = make_float2(Aq[ht], Bq[ht]);
            }
            // fold exclusive-q transforms into first gate pair (exact)
            #pragma unroll
            for (int ht = 0; ht < 4; ++ht) {
                const float Ae0 = __shfl_up(Aq[ht], 16), Be0 = __shfl_up(Bq[ht], 16);
                const float Aqe = (q == 0) ? 1.0f : Ae0;
                const float Bqe = (q == 0) ? 0.0f : Be0;
                gb[ht][0] = fmaf(ga[ht][0], Bqe, gb[ht][0]);
                ga[ht][0] = ga[ht][0] * Aqe;
            }
        }
        __syncthreads();   // A: all G1(c) s_h reads complete

        // ---- P1(c+1) overwrites s_h ----
        if (c + 1 < NC) {
            const int cp1 = c + 1;
            const unsigned bits = s_xb[2 * cp1 + (seg >> 1)] >> ((seg & 1) * 16);
            const float4 lt = s_lut[hidx];
            p1_scan(bits, lt.x, lt.y, lt.z, lt.w, seg, col0, carry0, s_h);
        }
        __syncthreads();   // B: s_h(c+1) ready
    }

    // ---- G2 for the last chunk ----
    g2_step(NC - 1);

    // ---- block partial (sum, sumsq) -> ws slot (plain stores) ----
    #pragma unroll
    for (int o = 32; o; o >>= 1) {
        lsum  += __shfl_down(lsum, o);
        lsum2 += __shfl_down(lsum2, o);
    }
    __syncthreads();                     // safe to reuse s_lut as scratch
    float* s_red = (float*)s_lut;
    if (lane == 0) { s_red[tg] = lsum; s_red[4 + tg] = lsum2; }
    __syncthreads();
    if (tid == 0) {
        const int gb2 = (b * 2 + (pm ? 1 : 0)) * 2 + z;
        ws[2 * gb2]     = s_red[0] + s_red[1] + s_red[2] + s_red[3];
        ws[2 * gb2 + 1] = s_red[4] + s_red[5] + s_red[6] + s_red[7];
    }
}

// Fold the 1024 block-partials (redundantly per block), normalize in-place.
__global__ void normalize_k(float* __restrict__ out, const float* __restrict__ ws)
{
    __shared__ float s_red[8];
    float s = 0.0f, s2 = 0.0f;
    for (int i = threadIdx.x; i < 4 * BB; i += 256) {
        s  += ws[2 * i];
        s2 += ws[2 * i + 1];
    }
    #pragma unroll
    for (int o = 32; o; o >>= 1) {
        s  += __shfl_down(s, o);
        s2 += __shfl_down(s2, o);
    }
    const int wid = threadIdx.x >> 6;
    if ((threadIdx.x & 63) == 0) { s_red[wid] = s; s_red[4 + wid] = s2; }
    __syncthreads();
    const float tot  = s_red[0] + s_red[1] + s_red[2] + s_red[3];
    const float tot2 = s_red[4] + s_red[5] + s_red[6] + s_red[7];
    const float N    = (float)NTOT;
    const float mean = tot / N;
    const float var  = (tot2 - N * mean * mean) / (N - 1.0f);
    const float inv  = rsqrtf(var);

    const int i = blockIdx.x * blockDim.x + threadIdx.x;   // exactly NTOT/4 threads
    float4* o4 = (float4*)out;
    float4 v = o4[i];
    v.x = (v.x - mean) * inv;
    v.y = (v.y - mean) * inv;
    v.z = (v.z - mean) * inv;
    v.w = (v.w - mean) * inv;
    o4[i] = v;
}

extern "C" void kernel_launch(void* const* d_in, const int* in_sizes, int n_in,
                              void* d_out, int out_size, void* d_ws, size_t ws_size,
                              hipStream_t stream)
{
    (void)in_sizes; (void)n_in; (void)out_size; (void)ws_size;
    const float* x = (const float*)d_in[0];
    const int*   p = (const int*)d_in[1];
    float* out = (float*)d_out;
    float* ws  = (float*)d_ws;

    dim3 grid(BB, 2, 2);
    gru_fused<<<grid, 256, 0, stream>>>(
        x, p,
        (const float*)d_in[2],  (const float*)d_in[3],
        (const float*)d_in[4],  (const float*)d_in[5],
        (const float*)d_in[6],  (const float*)d_in[7],
        (const float*)d_in[8],  (const float*)d_in[9],
        (const float*)d_in[10], (const float*)d_in[11],
        (const float*)d_in[12], (const float*)d_in[13],
        (const float*)d_in[14], (const float*)d_in[15],
        (const float*)d_in[16], (const float*)d_in[17],
        (const float*)d_in[18], (const float*)d_in[19],
        (const float*)d_in[20], (const float*)d_in[21],
        out, ws);

    normalize_k<<<NTOT / 4 / 256, 256, 0, stream>>>(out, ws);
}